// Round 1
// baseline (3561.186 us; speedup 1.0000x reference)
//
#include <hip/hip_runtime.h>

#define NB 128
#define NLQ 256   // sequence length L
#define ND 512    // feature dim D
#define NLAYERS 6

__device__ __forceinline__ float wave_max(float v){
  #pragma unroll
  for(int off=32; off; off>>=1) v = fmaxf(v, __shfl_xor(v, off));
  return v;
}
__device__ __forceinline__ float wave_sum(float v){
  #pragma unroll
  for(int off=32; off; off>>=1) v += __shfl_xor(v, off);
  return v;
}

// per-layer S0 = sum a1[0:256], S1 = sum a1[256:512]
__global__ __launch_bounds__(256) void k_scal(const float* __restrict__ a_stack,
                                              float* __restrict__ scal){
  int layer = blockIdx.x;
  const float* a = a_stack + (size_t)layer*2*ND;
  int t = threadIdx.x;
  float v0 = a[t];
  float v1 = a[256 + t];
  v0 = wave_sum(v0); v1 = wave_sum(v1);
  __shared__ float s0[4], s1[4];
  int wave = t>>6, lane = t&63;
  if(lane==0){ s0[wave]=v0; s1[wave]=v1; }
  __syncthreads();
  if(t==0){
    scal[layer*2+0] = s0[0]+s0[1]+s0[2]+s0[3];
    scal[layer*2+1] = s1[0]+s1[1]+s1[2]+s1[3];
  }
}

__global__ __launch_bounds__(256) void k_zero(float* __restrict__ p, int n){
  int i = blockIdx.x*256 + threadIdx.x;
  if(i < n) p[i] = 0.f;
}

// xp = position_weight(x)
__global__ __launch_bounds__(256) void k_posw(const float* __restrict__ x, float* __restrict__ xp,
    const int* __restrict__ left, const int* __restrict__ asp, const int* __restrict__ tl){
  int idx = blockIdx.x*256 + threadIdx.x;   // float4 index
  int b   = idx >> 15;                      // 32768 float4 per batch
  int rem = idx & 32767;
  int j   = rem >> 7;                       // 128 float4 per row
  float l = (float)left[b];
  float aspf = (float)asp[b];
  float r = l + aspf - 1.f;
  float tlf = (float)tl[b];
  float ctx = tlf - aspf;
  float jf = (float)j;
  float w;
  if(jf < l)        w = 1.f - (l - jf)/ctx;
  else if(jf <= r)  w = 0.f;
  else if(jf < tlf) w = 1.f - (jf - r)/ctx;
  else              w = 0.f;
  float4 v = ((const float4*)x)[idx];
  v.x *= w; v.y *= w; v.z *= w; v.w *= w;
  ((float4*)xp)[idx] = v;
}

// C[M,512] = A[M,512] @ W[512,512], fp32, 64x64 tile, 4x4 per thread
#define BMT 64
#define BNT 64
#define BKT 16
__global__ __launch_bounds__(256) void k_gemm(const float* __restrict__ A,
                                              const float* __restrict__ W,
                                              float* __restrict__ C){
  __shared__ float As[BKT][BMT+1];
  __shared__ float Ws[BKT][BNT+1];
  int bx = blockIdx.x & 7;       // 512/64 = 8 col tiles
  int by = blockIdx.x >> 3;
  int tx = threadIdx.x & 15;
  int ty = threadIdx.x >> 4;
  float acc[4][4] = {};
  for(int k0=0; k0<ND; k0+=BKT){
    #pragma unroll
    for(int u=0; u<4; u++){
      int idx = threadIdx.x + u*256;        // 0..1023
      int row = idx >> 4;
      int kk  = idx & 15;
      As[kk][row] = A[((size_t)(by*BMT + row))*ND + k0 + kk];
      int kk2 = idx >> 6;
      int col = idx & 63;
      Ws[kk2][col] = W[(size_t)(k0 + kk2)*ND + bx*BNT + col];
    }
    __syncthreads();
    #pragma unroll
    for(int kk=0; kk<BKT; kk++){
      float av[4], wv[4];
      #pragma unroll
      for(int q=0;q<4;q++) av[q] = As[kk][ty*4+q];
      #pragma unroll
      for(int q=0;q<4;q++) wv[q] = Ws[kk][tx*4+q];
      #pragma unroll
      for(int p=0;p<4;p++)
        #pragma unroll
        for(int q=0;q<4;q++) acc[p][q] += av[p]*wv[q];
    }
    __syncthreads();
  }
  #pragma unroll
  for(int p=0;p<4;p++)
    #pragma unroll
    for(int q=0;q<4;q++)
      C[((size_t)(by*BMT + ty*4 + p))*ND + bx*BNT + tx*4 + q] = acc[p][q];
}

// t[b,j] = h[b,j,:] . a2
__global__ __launch_bounds__(256) void k_t(const float* __restrict__ h,
                                           const float* __restrict__ a2,
                                           float* __restrict__ t){
  int row  = blockIdx.x*4 + (threadIdx.x>>6);
  int lane = threadIdx.x & 63;
  const float* hr = h + (size_t)row*ND;
  float s = 0.f;
  #pragma unroll
  for(int d=lane; d<ND; d+=64) s += hr[d]*a2[d];
  s = wave_sum(s);
  if(lane==0) t[row] = s;
}

// layer-0 full attention: one block per (b,i) row; writes h1 = posw(relu(att@h))
__global__ __launch_bounds__(256) void k_attn0(const float* __restrict__ h,
    const int* __restrict__ adj, const float* __restrict__ t,
    const float* __restrict__ scal, const int* __restrict__ left,
    const int* __restrict__ asp, const int* __restrict__ tl,
    float* __restrict__ h1){
  int b = blockIdx.x >> 8;
  int i = blockIdx.x & 255;
  int j = threadIdx.x;
  float S0 = scal[0], S1 = scal[1];
  const float* hb = h + (size_t)b*NLQ*ND;
  float2 hp = ((const float2*)(hb + (size_t)i*ND))[j];
  float e = fmaxf(S0*hp.x + S1*hp.y + t[b*NLQ + j], 0.f);
  int av = adj[((size_t)b*NLQ + i)*NLQ + j];
  if(av <= 0) e = -1e30f;
  __shared__ float red[4];
  __shared__ float atts[256];
  int wave = j>>6, lane = j&63;
  float m = wave_max(e);
  if(lane==0) red[wave] = m;
  __syncthreads();
  m = fmaxf(fmaxf(red[0],red[1]), fmaxf(red[2],red[3]));
  float p = (av > 0) ? __expf(e - m) : 0.f;
  __syncthreads();
  float s = wave_sum(p);
  if(lane==0) red[wave] = s;
  __syncthreads();
  s = red[0]+red[1]+red[2]+red[3];
  atts[j] = p/s;
  __syncthreads();
  float acc0=0.f, acc1=0.f;
  for(int jj=0; jj<NLQ; jj++){
    float a = atts[jj];
    if(a != 0.f){
      acc0 += a * hb[(size_t)jj*ND + j];
      acc1 += a * hb[(size_t)jj*ND + 256 + j];
    }
  }
  float l=(float)left[b], aspf=(float)asp[b], tlf=(float)tl[b];
  float r=l+aspf-1.f, ctx=tlf-aspf, fi=(float)i;
  float w;
  if(fi < l)        w = 1.f - (l - fi)/ctx;
  else if(fi <= r)  w = 0.f;
  else if(fi < tlf) w = 1.f - (fi - r)/ctx;
  else              w = 0.f;
  float* o = h1 + ((size_t)b*NLQ + i)*ND;
  o[j]       = w*fmaxf(acc0, 0.f);
  o[256 + j] = w*fmaxf(acc1, 0.f);
}

// layers >=1: attention only for aspect rows; g[b,:] += 0.2*relu(row). One block per b (deterministic).
__global__ __launch_bounds__(256) void k_aspect(const float* __restrict__ h,
    const int* __restrict__ adj, const float* __restrict__ t,
    const float* __restrict__ scal, const int* __restrict__ left,
    const int* __restrict__ asp, float* __restrict__ g){
  int b = blockIdx.x;
  int nk = asp[b];
  int l0 = left[b];
  int j = threadIdx.x;
  float S0 = scal[0], S1 = scal[1];
  const float* hb = h + (size_t)b*NLQ*ND;
  float tb = t[b*NLQ + j];
  __shared__ float red[4];
  __shared__ float atts[256];
  int wave = j>>6, lane = j&63;
  float gacc0 = 0.f, gacc1 = 0.f;
  for(int k=0; k<nk; k++){
    int i = l0 + k;
    float2 hp = ((const float2*)(hb + (size_t)i*ND))[j];
    float e = fmaxf(S0*hp.x + S1*hp.y + tb, 0.f);
    int av = adj[((size_t)b*NLQ + i)*NLQ + j];
    if(av <= 0) e = -1e30f;
    float m = wave_max(e);
    if(lane==0) red[wave] = m;
    __syncthreads();
    m = fmaxf(fmaxf(red[0],red[1]), fmaxf(red[2],red[3]));
    float p = (av > 0) ? __expf(e - m) : 0.f;
    __syncthreads();
    float s = wave_sum(p);
    if(lane==0) red[wave] = s;
    __syncthreads();
    s = red[0]+red[1]+red[2]+red[3];
    atts[j] = p/s;
    __syncthreads();
    float acc0=0.f, acc1=0.f;
    for(int jj=0; jj<NLQ; jj++){
      float a = atts[jj];
      if(a != 0.f){
        acc0 += a * hb[(size_t)jj*ND + j];
        acc1 += a * hb[(size_t)jj*ND + 256 + j];
      }
    }
    gacc0 += 0.2f*fmaxf(acc0, 0.f);
    gacc1 += 0.2f*fmaxf(acc1, 0.f);
    __syncthreads();
  }
  g[b*ND + j]       += gacc0;
  g[b*ND + 256 + j] += gacc1;
}

// final: s[m] = g[b].x[b,m]; alpha = softmax(s); out[b,:] = sum_m alpha[m] x[b,m,:]
__global__ __launch_bounds__(256) void k_final(const float* __restrict__ x,
                                               const float* __restrict__ g,
                                               float* __restrict__ out){
  int b = blockIdx.x;
  int m = threadIdx.x;
  const float* xb = x + (size_t)b*NLQ*ND;
  const float* gb = g + b*ND;
  __shared__ float gs[ND];
  gs[m] = gb[m]; gs[256+m] = gb[256+m];
  __syncthreads();
  float s = 0.f;
  const float4* xr = (const float4*)(xb + (size_t)m*ND);
  const float4* g4 = (const float4*)gs;
  for(int d4=0; d4<ND/4; d4++){
    float4 xv = xr[d4]; float4 gv = g4[d4];
    s += xv.x*gv.x + xv.y*gv.y + xv.z*gv.z + xv.w*gv.w;
  }
  __shared__ float red[4];
  __shared__ float alpha[256];
  int wave = m>>6, lane = m&63;
  float mx = wave_max(s);
  if(lane==0) red[wave] = mx;
  __syncthreads();
  mx = fmaxf(fmaxf(red[0],red[1]), fmaxf(red[2],red[3]));
  float p = __expf(s - mx);
  __syncthreads();
  float su = wave_sum(p);
  if(lane==0) red[wave] = su;
  __syncthreads();
  su = red[0]+red[1]+red[2]+red[3];
  alpha[m] = p/su;
  __syncthreads();
  float acc0=0.f, acc1=0.f;
  for(int mm=0; mm<NLQ; mm++){
    float a = alpha[mm];
    acc0 += a * xb[(size_t)mm*ND + m];
    acc1 += a * xb[(size_t)mm*ND + 256 + m];
  }
  out[b*ND + m]       = acc0;
  out[b*ND + 256 + m] = acc1;
}

extern "C" void kernel_launch(void* const* d_in, const int* in_sizes, int n_in,
                              void* d_out, int out_size, void* d_ws, size_t ws_size,
                              hipStream_t stream){
  const float* x    = (const float*)d_in[0];
  const float* Wst  = (const float*)d_in[1];
  const float* ast  = (const float*)d_in[2];
  const int*   adj  = (const int*)d_in[3];
  const int*   left = (const int*)d_in[4];
  const int*   asp  = (const int*)d_in[5];
  const int*   tl   = (const int*)d_in[6];
  float* out = (float*)d_out;
  float* ws  = (float*)d_ws;

  const size_t SZ = (size_t)NB*NLQ*ND;   // 16,777,216 floats
  float* bufA = ws;              // xp, then h1
  float* bufB = ws + SZ;         // h0 / h_i
  float* tbuf = ws + 2*SZ;       // B*L
  float* g    = tbuf + NB*NLQ;   // B*D
  float* scal = g + NB*ND;       // 2*NLAYERS

  k_scal<<<NLAYERS, 256, 0, stream>>>(ast, scal);
  k_zero<<<(NB*ND + 255)/256, 256, 0, stream>>>(g, NB*ND);
  k_posw<<<NB*NLQ*ND/1024, 256, 0, stream>>>(x, bufA, left, asp, tl);

  // layer 0: h0 = xp @ W0; full attention -> h1 (with posw) into bufA
  k_gemm<<<(NB*NLQ/BMT)*(ND/BNT), 256, 0, stream>>>(bufA, Wst, bufB);
  k_t<<<NB*NLQ/4, 256, 0, stream>>>(bufB, ast + ND, tbuf);
  k_attn0<<<NB*NLQ, 256, 0, stream>>>(bufB, adj, tbuf, scal, left, asp, tl, bufA);

  for(int layer=1; layer<NLAYERS; layer++){
    k_gemm<<<(NB*NLQ/BMT)*(ND/BNT), 256, 0, stream>>>(bufA, Wst + (size_t)layer*ND*ND, bufB);
    k_t<<<NB*NLQ/4, 256, 0, stream>>>(bufB, ast + (size_t)layer*2*ND + ND, tbuf);
    k_aspect<<<NB, 256, 0, stream>>>(bufB, adj, tbuf, scal + 2*layer, left, asp, g);
  }

  k_final<<<NB, 256, 0, stream>>>(x, g, out);
}

// Round 2
// 786.687 us; speedup vs baseline: 4.5268x; 4.5268x over previous
//
#include <hip/hip_runtime.h>

#define NB 128
#define NLQ 256   // sequence length L
#define ND 512    // feature dim D
#define NLAYERS 6

typedef short bf16x8 __attribute__((ext_vector_type(8)));
typedef float f32x4 __attribute__((ext_vector_type(4)));
typedef unsigned int u32x2 __attribute__((ext_vector_type(2)));

__device__ __forceinline__ float wave_max(float v){
  #pragma unroll
  for(int off=32; off; off>>=1) v = fmaxf(v, __shfl_xor(v, off));
  return v;
}
__device__ __forceinline__ float wave_sum(float v){
  #pragma unroll
  for(int off=32; off; off>>=1) v += __shfl_xor(v, off);
  return v;
}

// split two fp32 into packed bf16 hi-plane word and lo-plane word (truncation split;
// hi+lo reproduces x to ~2^-16 relative)
__device__ __forceinline__ void split2(float x0, float x1, unsigned int& hi, unsigned int& lo){
  unsigned int u0 = __float_as_uint(x0), u1 = __float_as_uint(x1);
  unsigned int h0 = u0 & 0xFFFF0000u, h1 = u1 & 0xFFFF0000u;
  hi = (u0 >> 16) | h1;
  float d0 = x0 - __uint_as_float(h0);
  float d1 = x1 - __uint_as_float(h1);
  lo = (__float_as_uint(d0) >> 16) | (__float_as_uint(d1) & 0xFFFF0000u);
}

// per-layer S0 = sum a1[0:256], S1 = sum a1[256:512]
__global__ __launch_bounds__(256) void k_scal(const float* __restrict__ a_stack,
                                              float* __restrict__ scal){
  int layer = blockIdx.x;
  const float* a = a_stack + (size_t)layer*2*ND;
  int t = threadIdx.x;
  float v0 = a[t];
  float v1 = a[256 + t];
  v0 = wave_sum(v0); v1 = wave_sum(v1);
  __shared__ float s0[4], s1[4];
  int wave = t>>6, lane = t&63;
  if(lane==0){ s0[wave]=v0; s1[wave]=v1; }
  __syncthreads();
  if(t==0){
    scal[layer*2+0] = s0[0]+s0[1]+s0[2]+s0[3];
    scal[layer*2+1] = s1[0]+s1[1]+s1[2]+s1[3];
  }
}

__global__ __launch_bounds__(256) void k_zero(float* __restrict__ p, int n){
  int i = blockIdx.x*256 + threadIdx.x;
  if(i < n) p[i] = 0.f;
}

// xp = position_weight(x)
__global__ __launch_bounds__(256) void k_posw(const float* __restrict__ x, float* __restrict__ xp,
    const int* __restrict__ left, const int* __restrict__ asp, const int* __restrict__ tl){
  int idx = blockIdx.x*256 + threadIdx.x;   // float4 index
  int b   = idx >> 15;                      // 32768 float4 per batch
  int rem = idx & 32767;
  int j   = rem >> 7;                       // 128 float4 per row
  float l = (float)left[b];
  float aspf = (float)asp[b];
  float r = l + aspf - 1.f;
  float tlf = (float)tl[b];
  float ctx = tlf - aspf;
  float jf = (float)j;
  float w;
  if(jf < l)        w = 1.f - (l - jf)/ctx;
  else if(jf <= r)  w = 0.f;
  else if(jf < tlf) w = 1.f - (jf - r)/ctx;
  else              w = 0.f;
  float4 v = ((const float4*)x)[idx];
  v.x *= w; v.y *= w; v.z *= w; v.w *= w;
  ((float4*)xp)[idx] = v;
}

// C[M,512] = A[M,512] @ W[512,512] via split-bf16 MFMA (3-term: Ah*Wh + Ah*Wl + Al*Wh)
// 128x128 tile, BK=32, 256 threads = 4 waves in 2x2 grid, each wave 64x64 (4x4 frags 16x16x32)
#define ROWB 80   // padded LDS row bytes (32 bf16 = 64B data + 16B pad -> conflict-light)
__global__ __launch_bounds__(256) void k_gemm(const float* __restrict__ A,
                                              const float* __restrict__ W,
                                              float* __restrict__ C){
  __shared__ unsigned char lds[4*128*ROWB];
  unsigned char* Ahi = lds;
  unsigned char* Alo = lds + 128*ROWB;
  unsigned char* Bhi = lds + 2*128*ROWB;
  unsigned char* Blo = lds + 3*128*ROWB;

  int t = threadIdx.x;
  int ntile = blockIdx.x & 3;
  int mtile = blockIdx.x >> 2;
  int m0 = mtile*128, n0 = ntile*128;

  int lane = t & 63, wid = t >> 6;
  int wr = wid >> 1, wc = wid & 1;
  int lrow = lane & 15, kb = lane >> 4;

  f32x4 acc[4][4];
  #pragma unroll
  for(int mi=0;mi<4;mi++)
    #pragma unroll
    for(int ni=0;ni<4;ni++)
      acc[mi][ni] = (f32x4){0.f,0.f,0.f,0.f};

  // staging roles
  int a_row = t >> 3;          // 0..31 (+p*32)
  int a_kq  = t & 7;           // float4 slot within 32-k row
  int w_n   = t & 127;         // n within tile
  int w_half= t >> 7;          // 0/1 -> k half

  float4 pa[4];
  float  pw[16];

  // prefetch k0 = 0
  #pragma unroll
  for(int p=0;p<4;p++)
    pa[p] = *(const float4*)(A + (size_t)(m0 + a_row + p*32)*ND + a_kq*4);
  #pragma unroll
  for(int q=0;q<4;q++){
    const float* wp = W + (size_t)(w_half*16 + q*4)*ND + n0 + w_n;
    pw[q*4+0]=wp[0]; pw[q*4+1]=wp[ND]; pw[q*4+2]=wp[2*ND]; pw[q*4+3]=wp[3*ND];
  }

  for(int k0=0; k0<ND; k0+=32){
    // ---- write staged regs to LDS (split hi/lo) ----
    #pragma unroll
    for(int p=0;p<4;p++){
      int row = a_row + p*32;
      unsigned int h01, l01, h23, l23;
      split2(pa[p].x, pa[p].y, h01, l01);
      split2(pa[p].z, pa[p].w, h23, l23);
      int off = row*ROWB + a_kq*8;
      *(u32x2*)(Ahi + off) = (u32x2){h01, h23};
      *(u32x2*)(Alo + off) = (u32x2){l01, l23};
    }
    #pragma unroll
    for(int q=0;q<4;q++){
      unsigned int h01, l01, h23, l23;
      split2(pw[q*4+0], pw[q*4+1], h01, l01);
      split2(pw[q*4+2], pw[q*4+3], h23, l23);
      int off = w_n*ROWB + (w_half*4 + q)*8;
      *(u32x2*)(Bhi + off) = (u32x2){h01, h23};
      *(u32x2*)(Blo + off) = (u32x2){l01, l23};
    }
    __syncthreads();

    // ---- prefetch next K tile (overlaps with MFMA below) ----
    if(k0 + 32 < ND){
      int kn = k0 + 32;
      #pragma unroll
      for(int p=0;p<4;p++)
        pa[p] = *(const float4*)(A + (size_t)(m0 + a_row + p*32)*ND + kn + a_kq*4);
      #pragma unroll
      for(int q=0;q<4;q++){
        const float* wp = W + (size_t)(kn + w_half*16 + q*4)*ND + n0 + w_n;
        pw[q*4+0]=wp[0]; pw[q*4+1]=wp[ND]; pw[q*4+2]=wp[2*ND]; pw[q*4+3]=wp[3*ND];
      }
    }

    // ---- fragment loads ----
    bf16x8 ah[4], al[4], bh[4], bl[4];
    #pragma unroll
    for(int mi=0;mi<4;mi++){
      int r = wr*64 + mi*16 + lrow;
      int off = r*ROWB + kb*16;
      ah[mi] = *(const bf16x8*)(Ahi + off);
      al[mi] = *(const bf16x8*)(Alo + off);
    }
    #pragma unroll
    for(int ni=0;ni<4;ni++){
      int n = wc*64 + ni*16 + lrow;
      int off = n*ROWB + kb*16;
      bh[ni] = *(const bf16x8*)(Bhi + off);
      bl[ni] = *(const bf16x8*)(Blo + off);
    }

    // ---- MFMA: 3-term split product ----
    #pragma unroll
    for(int mi=0;mi<4;mi++)
      #pragma unroll
      for(int ni=0;ni<4;ni++){
        acc[mi][ni] = __builtin_amdgcn_mfma_f32_16x16x32_bf16(ah[mi], bh[ni], acc[mi][ni], 0,0,0);
        acc[mi][ni] = __builtin_amdgcn_mfma_f32_16x16x32_bf16(ah[mi], bl[ni], acc[mi][ni], 0,0,0);
        acc[mi][ni] = __builtin_amdgcn_mfma_f32_16x16x32_bf16(al[mi], bh[ni], acc[mi][ni], 0,0,0);
      }
    __syncthreads();
  }

  // epilogue: C/D layout col = lane&15, row = (lane>>4)*4 + q
  int rg = lane >> 4;
  int cc = lane & 15;
  #pragma unroll
  for(int mi=0;mi<4;mi++){
    #pragma unroll
    for(int ni=0;ni<4;ni++){
      int col = n0 + wc*64 + ni*16 + cc;
      #pragma unroll
      for(int q=0;q<4;q++){
        int row = m0 + wr*64 + mi*16 + rg*4 + q;
        C[(size_t)row*ND + col] = acc[mi][ni][q];
      }
    }
  }
}

// t[row] = h[row,:] . a2
__global__ __launch_bounds__(256) void k_t(const float* __restrict__ h,
                                           const float* __restrict__ a2,
                                           float* __restrict__ t){
  int row  = blockIdx.x*4 + (threadIdx.x>>6);
  int lane = threadIdx.x & 63;
  const float4* hr = (const float4*)(h + (size_t)row*ND);
  const float4* a4 = (const float4*)a2;
  float s = 0.f;
  #pragma unroll
  for(int q=0;q<2;q++){
    float4 hv = hr[lane + 64*q];
    float4 av = a4[lane + 64*q];
    s += hv.x*av.x + hv.y*av.y + hv.z*av.z + hv.w*av.w;
  }
  s = wave_sum(s);
  if(lane==0) t[row] = s;
}

// layer-0 full attention: 32 i-rows per block, 8 blocks per batch.
// h1 = posw(relu(att @ h))
__global__ __launch_bounds__(256) void k_attn0(const float* __restrict__ h,
    const int* __restrict__ adj, const float* __restrict__ t,
    const float* __restrict__ scal, const int* __restrict__ left,
    const int* __restrict__ asp, const int* __restrict__ tl,
    float* __restrict__ h1){
  __shared__ float att[256*36];   // [jj][ii], stride 36 (16B-aligned rows)
  int b  = blockIdx.x >> 3;
  int i0 = (blockIdx.x & 7) * 32;
  int tid = threadIdx.x;
  int lane = tid & 63, w = tid >> 6;
  float S0 = scal[0], S1 = scal[1];
  const float* hb = h + (size_t)b*NLQ*ND;

  float tb[4];
  #pragma unroll
  for(int q=0;q<4;q++) tb[q] = t[b*NLQ + lane + 64*q];

  // phase 1: each wave computes softmax for 8 rows
  for(int rr=0; rr<8; rr++){
    int i = i0 + w*8 + rr;
    const float2* hrow = (const float2*)(hb + (size_t)i*ND);
    const int* arow = adj + ((size_t)b*NLQ + i)*NLQ;
    float e[4]; int av[4];
    float m = -3.0e38f;
    #pragma unroll
    for(int q=0;q<4;q++){
      int j = lane + 64*q;
      float2 hp = hrow[j];
      av[q] = arow[j];
      e[q] = fmaxf(S0*hp.x + S1*hp.y + tb[q], 0.f);
      if(av[q] > 0) m = fmaxf(m, e[q]);
    }
    m = wave_max(m);
    float p[4]; float s = 0.f;
    #pragma unroll
    for(int q=0;q<4;q++){
      p[q] = (av[q] > 0) ? __expf(e[q]-m) : 0.f;
      s += p[q];
    }
    s = wave_sum(s);
    float inv = 1.f/s;
    #pragma unroll
    for(int q=0;q<4;q++) att[(lane+64*q)*36 + (w*8+rr)] = p[q]*inv;
  }
  __syncthreads();

  // phase 2: aggregate; thread owns cols d and d+256
  int d = tid;
  float accx[32], accy[32];
  #pragma unroll
  for(int ii=0;ii<32;ii++){ accx[ii]=0.f; accy[ii]=0.f; }
  for(int jj=0; jj<NLQ; jj++){
    float hx = hb[(size_t)jj*ND + d];
    float hy = hb[(size_t)jj*ND + 256 + d];
    const float4* ar = (const float4*)(att + jj*36);
    #pragma unroll
    for(int c=0;c<8;c++){
      float4 a4 = ar[c];
      accx[4*c+0] += a4.x*hx; accy[4*c+0] += a4.x*hy;
      accx[4*c+1] += a4.y*hx; accy[4*c+1] += a4.y*hy;
      accx[4*c+2] += a4.z*hx; accy[4*c+2] += a4.z*hy;
      accx[4*c+3] += a4.w*hx; accy[4*c+3] += a4.w*hy;
    }
  }

  float l=(float)left[b], aspf=(float)asp[b], tlf=(float)tl[b];
  float r=l+aspf-1.f, ctx=tlf-aspf;
  #pragma unroll
  for(int ii=0;ii<32;ii++){
    float fi = (float)(i0+ii);
    float wgt;
    if(fi < l)        wgt = 1.f-(l-fi)/ctx;
    else if(fi <= r)  wgt = 0.f;
    else if(fi < tlf) wgt = 1.f-(fi-r)/ctx;
    else              wgt = 0.f;
    float* o = h1 + ((size_t)b*NLQ + i0+ii)*ND;
    o[d]       = wgt*fmaxf(accx[ii], 0.f);
    o[256 + d] = wgt*fmaxf(accy[ii], 0.f);
  }
}

// layers >=1: only aspect rows matter. One block per batch; rows' softmax done
// wave-parallel, single fused aggregation pass, deterministic g accumulation.
__global__ __launch_bounds__(256) void k_aspect(const float* __restrict__ h,
    const int* __restrict__ adj, const float* __restrict__ t,
    const float* __restrict__ scal, const int* __restrict__ left,
    const int* __restrict__ asp, float* __restrict__ g){
  __shared__ float att[5*257];
  int b = blockIdx.x;
  int tid = threadIdx.x, lane = tid & 63, w = tid >> 6;
  int nk = asp[b], l0 = left[b];
  float S0 = scal[0], S1 = scal[1];
  const float* hb = h + (size_t)b*NLQ*ND;

  for(int k = w; k < 5; k += 4){
    if(k < nk){
      int i = l0 + k;
      const float2* hrow = (const float2*)(hb + (size_t)i*ND);
      const int* arow = adj + ((size_t)b*NLQ + i)*NLQ;
      float e[4]; int av[4];
      float m = -3.0e38f;
      #pragma unroll
      for(int q=0;q<4;q++){
        int j = lane + 64*q;
        float2 hp = hrow[j];
        av[q] = arow[j];
        e[q] = fmaxf(S0*hp.x + S1*hp.y + t[b*NLQ + j], 0.f);
        if(av[q] > 0) m = fmaxf(m, e[q]);
      }
      m = wave_max(m);
      float p[4]; float s = 0.f;
      #pragma unroll
      for(int q=0;q<4;q++){
        p[q] = (av[q] > 0) ? __expf(e[q]-m) : 0.f;
        s += p[q];
      }
      s = wave_sum(s);
      float inv = 1.f/s;
      #pragma unroll
      for(int q=0;q<4;q++) att[k*257 + lane + 64*q] = p[q]*inv;
    } else {
      #pragma unroll
      for(int q=0;q<4;q++) att[k*257 + lane + 64*q] = 0.f;
    }
  }
  __syncthreads();

  int d = tid;
  float accx[5], accy[5];
  #pragma unroll
  for(int k=0;k<5;k++){ accx[k]=0.f; accy[k]=0.f; }
  for(int jj=0; jj<NLQ; jj++){
    float hx = hb[(size_t)jj*ND + d];
    float hy = hb[(size_t)jj*ND + 256 + d];
    #pragma unroll
    for(int k=0;k<5;k++){
      float a = att[k*257 + jj];
      accx[k] += a*hx;
      accy[k] += a*hy;
    }
  }
  float gx=0.f, gy=0.f;
  #pragma unroll
  for(int k=0;k<5;k++){
    if(k < nk){
      gx += fmaxf(accx[k], 0.f);
      gy += fmaxf(accy[k], 0.f);
    }
  }
  g[b*ND + d]       += 0.2f*gx;
  g[b*ND + 256 + d] += 0.2f*gy;
}

// final: s[m] = g[b].x[b,m]; alpha = softmax(s); out[b,:] = sum_m alpha[m] x[b,m,:]
__global__ __launch_bounds__(256) void k_final(const float* __restrict__ x,
                                               const float* __restrict__ g,
                                               float* __restrict__ out){
  int b = blockIdx.x;
  int m = threadIdx.x;
  const float* xb = x + (size_t)b*NLQ*ND;
  const float* gb = g + b*ND;
  __shared__ float gs[ND];
  gs[m] = gb[m]; gs[256+m] = gb[256+m];
  __syncthreads();
  float s = 0.f;
  const float4* xr = (const float4*)(xb + (size_t)m*ND);
  const float4* g4 = (const float4*)gs;
  for(int d4=0; d4<ND/4; d4++){
    float4 xv = xr[d4]; float4 gv = g4[d4];
    s += xv.x*gv.x + xv.y*gv.y + xv.z*gv.z + xv.w*gv.w;
  }
  __shared__ float red[4];
  __shared__ float alpha[256];
  int wave = m>>6, lane = m&63;
  float mx = wave_max(s);
  if(lane==0) red[wave] = mx;
  __syncthreads();
  mx = fmaxf(fmaxf(red[0],red[1]), fmaxf(red[2],red[3]));
  float p = __expf(s - mx);
  __syncthreads();
  float su = wave_sum(p);
  if(lane==0) red[wave] = su;
  __syncthreads();
  su = red[0]+red[1]+red[2]+red[3];
  alpha[m] = p/su;
  __syncthreads();
  float acc0=0.f, acc1=0.f;
  for(int mm=0; mm<NLQ; mm++){
    float a = alpha[mm];
    acc0 += a * xb[(size_t)mm*ND + m];
    acc1 += a * xb[(size_t)mm*ND + 256 + m];
  }
  out[b*ND + m]       = acc0;
  out[b*ND + 256 + m] = acc1;
}

extern "C" void kernel_launch(void* const* d_in, const int* in_sizes, int n_in,
                              void* d_out, int out_size, void* d_ws, size_t ws_size,
                              hipStream_t stream){
  const float* x    = (const float*)d_in[0];
  const float* Wst  = (const float*)d_in[1];
  const float* ast  = (const float*)d_in[2];
  const int*   adj  = (const int*)d_in[3];
  const int*   left = (const int*)d_in[4];
  const int*   asp  = (const int*)d_in[5];
  const int*   tl   = (const int*)d_in[6];
  float* out = (float*)d_out;
  float* ws  = (float*)d_ws;

  const size_t SZ = (size_t)NB*NLQ*ND;   // 16,777,216 floats
  float* bufA = ws;              // xp, then h1 (fp32)
  float* bufB = ws + SZ;         // h (fp32 GEMM output)
  float* tbuf = ws + 2*SZ;       // B*L
  float* g    = tbuf + NB*NLQ;   // B*D
  float* scal = g + NB*ND;       // 2*NLAYERS

  k_scal<<<NLAYERS, 256, 0, stream>>>(ast, scal);
  k_zero<<<(NB*ND + 255)/256, 256, 0, stream>>>(g, NB*ND);
  k_posw<<<NB*NLQ*ND/1024, 256, 0, stream>>>(x, bufA, left, asp, tl);

  // layer 0: h = xp @ W0 (MFMA), t, full attention -> h1 (posw'd) into bufA
  k_gemm<<<(NB*NLQ/128)*(ND/128), 256, 0, stream>>>(bufA, Wst, bufB);
  k_t<<<NB*NLQ/4, 256, 0, stream>>>(bufB, ast + ND, tbuf);
  k_attn0<<<NB*8, 256, 0, stream>>>(bufB, adj, tbuf, scal, left, asp, tl, bufA);

  for(int layer=1; layer<NLAYERS; layer++){
    k_gemm<<<(NB*NLQ/128)*(ND/128), 256, 0, stream>>>(bufA, Wst + (size_t)layer*ND*ND, bufB);
    k_t<<<NB*NLQ/4, 256, 0, stream>>>(bufB, ast + (size_t)layer*2*ND + ND, tbuf);
    k_aspect<<<NB, 256, 0, stream>>>(bufB, adj, tbuf, scal + 2*layer, left, asp, g);
  }

  k_final<<<NB, 256, 0, stream>>>(x, g, out);
}

// Round 3
// 395.272 us; speedup vs baseline: 9.0095x; 1.9902x over previous
//
#include <hip/hip_runtime.h>

#define NB 128
#define NLQ 256   // sequence length L
#define ND 512    // feature dim D
#define NLAYERS 6
#define DD (ND*ND)
#define MN (1024*ND)

typedef short bf16x8 __attribute__((ext_vector_type(8)));
typedef float f32x4 __attribute__((ext_vector_type(4)));
typedef unsigned int u32x2 __attribute__((ext_vector_type(2)));

__device__ __forceinline__ float wave_max(float v){
  #pragma unroll
  for(int off=32; off; off>>=1) v = fmaxf(v, __shfl_xor(v, off));
  return v;
}
__device__ __forceinline__ float wave_sum(float v){
  #pragma unroll
  for(int off=32; off; off>>=1) v += __shfl_xor(v, off);
  return v;
}

__device__ __forceinline__ void split2(float x0, float x1, unsigned int& hi, unsigned int& lo){
  unsigned int u0 = __float_as_uint(x0), u1 = __float_as_uint(x1);
  unsigned int h0 = u0 & 0xFFFF0000u, h1 = u1 & 0xFFFF0000u;
  hi = (u0 >> 16) | h1;
  float d0 = x0 - __uint_as_float(h0);
  float d1 = x1 - __uint_as_float(h1);
  lo = (__float_as_uint(d0) >> 16) | (__float_as_uint(d1) & 0xFFFF0000u);
}

// per-layer S0 = sum a1[0:256], S1 = sum a1[256:512]
__global__ __launch_bounds__(256) void k_scal(const float* __restrict__ a_stack,
                                              float* __restrict__ scal){
  int layer = blockIdx.x;
  const float* a = a_stack + (size_t)layer*2*ND;
  int t = threadIdx.x;
  float v0 = a[t];
  float v1 = a[256 + t];
  v0 = wave_sum(v0); v1 = wave_sum(v1);
  __shared__ float s0[4], s1[4];
  int wave = t>>6, lane = t&63;
  if(lane==0){ s0[wave]=v0; s1[wave]=v1; }
  __syncthreads();
  if(t==0){
    scal[layer*2+0] = s0[0]+s0[1]+s0[2]+s0[3];
    scal[layer*2+1] = s1[0]+s1[1]+s1[2]+s1[3];
  }
}

// v_l = W_{l+1} . a2_{l+1}  (for layers 1..5), v[l][i] = dot(W[i,:], a2)
__global__ __launch_bounds__(256) void k_wa2(const float* __restrict__ Wst,
                                             const float* __restrict__ ast,
                                             float* __restrict__ v){
  int l  = blockIdx.x >> 7;        // 0..4 -> layer l+1
  int rg = blockIdx.x & 127;
  int i  = rg*4 + (threadIdx.x>>6);
  int lane = threadIdx.x & 63;
  const float4* wr = (const float4*)(Wst + (size_t)(l+1)*DD + (size_t)i*ND);
  const float4* ar = (const float4*)(ast + (size_t)(l+1)*2*ND + ND);
  float4 w0=wr[lane], w1=wr[lane+64], a0=ar[lane], a1=ar[lane+64];
  float d = w0.x*a0.x + w0.y*a0.y + w0.z*a0.z + w0.w*a0.w
          + w1.x*a1.x + w1.y*a1.y + w1.z*a1.z + w1.w*a1.w;
  d = wave_sum(d);
  if(lane==0) v[l*ND + i] = d;
}

// xp = position_weight(x)
__global__ __launch_bounds__(256) void k_posw(const float* __restrict__ x, float* __restrict__ xp,
    const int* __restrict__ left, const int* __restrict__ asp, const int* __restrict__ tl){
  int idx = blockIdx.x*256 + threadIdx.x;
  int b   = idx >> 15;
  int rem = idx & 32767;
  int j   = rem >> 7;
  float l = (float)left[b];
  float aspf = (float)asp[b];
  float r = l + aspf - 1.f;
  float tlf = (float)tl[b];
  float ctx = tlf - aspf;
  float jf = (float)j;
  float w;
  if(jf < l)        w = 1.f - (l - jf)/ctx;
  else if(jf <= r)  w = 0.f;
  else if(jf < tlf) w = 1.f - (jf - r)/ctx;
  else              w = 0.f;
  float4 v = ((const float4*)x)[idx];
  v.x *= w; v.y *= w; v.z *= w; v.w *= w;
  ((float4*)xp)[idx] = v;
}

// ---- split-bf16 MFMA GEMM tile body: C[128x128] += A[128xK]@W[Kx128] ----
#define ROWB 80
__device__ __forceinline__ void gemm_tile(const float* __restrict__ A,
                                          const float* __restrict__ W,
                                          float* __restrict__ C,
                                          int mtile, int ntile, unsigned char* lds){
  unsigned char* Ahi = lds;
  unsigned char* Alo = lds + 128*ROWB;
  unsigned char* Bhi = lds + 2*128*ROWB;
  unsigned char* Blo = lds + 3*128*ROWB;

  int t = threadIdx.x;
  int m0 = mtile*128, n0 = ntile*128;
  int lane = t & 63, wid = t >> 6;
  int wr = wid >> 1, wc = wid & 1;
  int lrow = lane & 15, kb = lane >> 4;

  f32x4 acc[4][4];
  #pragma unroll
  for(int mi=0;mi<4;mi++)
    #pragma unroll
    for(int ni=0;ni<4;ni++)
      acc[mi][ni] = (f32x4){0.f,0.f,0.f,0.f};

  int a_row = t >> 3;
  int a_kq  = t & 7;
  int w_n   = t & 127;
  int w_half= t >> 7;

  float4 pa[4];
  float  pw[16];

  #pragma unroll
  for(int p=0;p<4;p++)
    pa[p] = *(const float4*)(A + (size_t)(m0 + a_row + p*32)*ND + a_kq*4);
  #pragma unroll
  for(int q=0;q<4;q++){
    const float* wp = W + (size_t)(w_half*16 + q*4)*ND + n0 + w_n;
    pw[q*4+0]=wp[0]; pw[q*4+1]=wp[ND]; pw[q*4+2]=wp[2*ND]; pw[q*4+3]=wp[3*ND];
  }

  for(int k0=0; k0<ND; k0+=32){
    #pragma unroll
    for(int p=0;p<4;p++){
      int row = a_row + p*32;
      unsigned int h01, l01, h23, l23;
      split2(pa[p].x, pa[p].y, h01, l01);
      split2(pa[p].z, pa[p].w, h23, l23);
      int off = row*ROWB + a_kq*8;
      *(u32x2*)(Ahi + off) = (u32x2){h01, h23};
      *(u32x2*)(Alo + off) = (u32x2){l01, l23};
    }
    #pragma unroll
    for(int q=0;q<4;q++){
      unsigned int h01, l01, h23, l23;
      split2(pw[q*4+0], pw[q*4+1], h01, l01);
      split2(pw[q*4+2], pw[q*4+3], h23, l23);
      int off = w_n*ROWB + (w_half*4 + q)*8;
      *(u32x2*)(Bhi + off) = (u32x2){h01, h23};
      *(u32x2*)(Blo + off) = (u32x2){l01, l23};
    }
    __syncthreads();

    if(k0 + 32 < ND){
      int kn = k0 + 32;
      #pragma unroll
      for(int p=0;p<4;p++)
        pa[p] = *(const float4*)(A + (size_t)(m0 + a_row + p*32)*ND + kn + a_kq*4);
      #pragma unroll
      for(int q=0;q<4;q++){
        const float* wp = W + (size_t)(kn + w_half*16 + q*4)*ND + n0 + w_n;
        pw[q*4+0]=wp[0]; pw[q*4+1]=wp[ND]; pw[q*4+2]=wp[2*ND]; pw[q*4+3]=wp[3*ND];
      }
    }

    bf16x8 ah[4], al[4], bh[4], bl[4];
    #pragma unroll
    for(int mi=0;mi<4;mi++){
      int r = wr*64 + mi*16 + lrow;
      int off = r*ROWB + kb*16;
      ah[mi] = *(const bf16x8*)(Ahi + off);
      al[mi] = *(const bf16x8*)(Alo + off);
    }
    #pragma unroll
    for(int ni=0;ni<4;ni++){
      int n = wc*64 + ni*16 + lrow;
      int off = n*ROWB + kb*16;
      bh[ni] = *(const bf16x8*)(Bhi + off);
      bl[ni] = *(const bf16x8*)(Blo + off);
    }

    #pragma unroll
    for(int mi=0;mi<4;mi++)
      #pragma unroll
      for(int ni=0;ni<4;ni++){
        acc[mi][ni] = __builtin_amdgcn_mfma_f32_16x16x32_bf16(ah[mi], bh[ni], acc[mi][ni], 0,0,0);
        acc[mi][ni] = __builtin_amdgcn_mfma_f32_16x16x32_bf16(ah[mi], bl[ni], acc[mi][ni], 0,0,0);
        acc[mi][ni] = __builtin_amdgcn_mfma_f32_16x16x32_bf16(al[mi], bh[ni], acc[mi][ni], 0,0,0);
      }
    __syncthreads();
  }

  int rg = lane >> 4;
  int cc = lane & 15;
  #pragma unroll
  for(int mi=0;mi<4;mi++){
    #pragma unroll
    for(int ni=0;ni<4;ni++){
      int col = n0 + wc*64 + ni*16 + cc;
      #pragma unroll
      for(int q=0;q<4;q++){
        int row = m0 + wr*64 + mi*16 + rg*4 + q;
        C[(size_t)row*ND + col] = acc[mi][ni][q];
      }
    }
  }
}

__global__ __launch_bounds__(256) void k_gemm(const float* __restrict__ A,
                                              const float* __restrict__ W,
                                              float* __restrict__ C){
  __shared__ unsigned char lds[4*128*ROWB];
  gemm_tile(A, W, C, blockIdx.x>>2, blockIdx.x&3, lds);
}

// batched small GEMM over 5 layers: C_l[1024x512] = A_l[1024x512] @ W_{l+1}
__global__ __launch_bounds__(256) void k_gemm_b(const float* __restrict__ Abase, long aStride,
                                                const float* __restrict__ Wbase,
                                                float* __restrict__ Cbase){
  __shared__ unsigned char lds[4*128*ROWB];
  int l  = blockIdx.x >> 5;     // 32 tiles per layer
  int tb = blockIdx.x & 31;
  gemm_tile(Abase + (size_t)l*aStride, Wbase + (size_t)(l+1)*DD,
            Cbase + (size_t)l*MN, tb>>2, tb&3, lds);
}

// t[row] = h[row,:] . a2
__global__ __launch_bounds__(256) void k_t(const float* __restrict__ h,
                                           const float* __restrict__ a2,
                                           float* __restrict__ t){
  int row  = blockIdx.x*4 + (threadIdx.x>>6);
  int lane = threadIdx.x & 63;
  const float4* hr = (const float4*)(h + (size_t)row*ND);
  const float4* a4 = (const float4*)a2;
  float s = 0.f;
  #pragma unroll
  for(int q=0;q<2;q++){
    float4 hv = hr[lane + 64*q];
    float4 av = a4[lane + 64*q];
    s += hv.x*av.x + hv.y*av.y + hv.z*av.z + hv.w*av.w;
  }
  s = wave_sum(s);
  if(lane==0) t[row] = s;
}

// layer-0 full attention: 32 i-rows per block; batch-major block order for XCD/L2 locality
__global__ __launch_bounds__(256) void k_attn0(const float* __restrict__ h,
    const int* __restrict__ adj, const float* __restrict__ t,
    const float* __restrict__ scal, const int* __restrict__ left,
    const int* __restrict__ asp, const int* __restrict__ tl,
    float* __restrict__ h1){
  __shared__ float att[256*36];
  // decode: 4 phases of 256 blocks; within phase: chunk-major, batch-minor
  int bid = blockIdx.x;
  int p  = bid >> 8;
  int r  = bid & 255;
  int c  = r >> 5;
  int bb = r & 31;
  int b  = p*32 + bb;
  int i0 = c*32;
  int tid = threadIdx.x;
  int lane = tid & 63, w = tid >> 6;
  float S0 = scal[0], S1 = scal[1];
  const float* hb = h + (size_t)b*NLQ*ND;

  float tb[4];
  #pragma unroll
  for(int q=0;q<4;q++) tb[q] = t[b*NLQ + lane + 64*q];

  for(int rr=0; rr<8; rr++){
    int i = i0 + w*8 + rr;
    const float2* hrow = (const float2*)(hb + (size_t)i*ND);
    const int* arow = adj + ((size_t)b*NLQ + i)*NLQ;
    float e[4]; int av[4];
    float m = -3.0e38f;
    #pragma unroll
    for(int q=0;q<4;q++){
      int j = lane + 64*q;
      float2 hp = hrow[j];
      av[q] = arow[j];
      e[q] = fmaxf(S0*hp.x + S1*hp.y + tb[q], 0.f);
      if(av[q] > 0) m = fmaxf(m, e[q]);
    }
    m = wave_max(m);
    float pp[4]; float s = 0.f;
    #pragma unroll
    for(int q=0;q<4;q++){
      pp[q] = (av[q] > 0) ? __expf(e[q]-m) : 0.f;
      s += pp[q];
    }
    s = wave_sum(s);
    float inv = 1.f/s;
    #pragma unroll
    for(int q=0;q<4;q++) att[(lane+64*q)*36 + (w*8+rr)] = pp[q]*inv;
  }
  __syncthreads();

  int d = tid;
  float accx[32], accy[32];
  #pragma unroll
  for(int ii=0;ii<32;ii++){ accx[ii]=0.f; accy[ii]=0.f; }
  for(int jj=0; jj<NLQ; jj++){
    float hx = hb[(size_t)jj*ND + d];
    float hy = hb[(size_t)jj*ND + 256 + d];
    const float4* ar = (const float4*)(att + jj*36);
    #pragma unroll
    for(int cc=0;cc<8;cc++){
      float4 a4 = ar[cc];
      accx[4*cc+0] += a4.x*hx; accy[4*cc+0] += a4.x*hy;
      accx[4*cc+1] += a4.y*hx; accy[4*cc+1] += a4.y*hy;
      accx[4*cc+2] += a4.z*hx; accy[4*cc+2] += a4.z*hy;
      accx[4*cc+3] += a4.w*hx; accy[4*cc+3] += a4.w*hy;
    }
  }

  float l=(float)left[b], aspf=(float)asp[b], tlf=(float)tl[b];
  float rr2=l+aspf-1.f, ctx=tlf-aspf;
  #pragma unroll
  for(int ii=0;ii<32;ii++){
    float fi = (float)(i0+ii);
    float wgt;
    if(fi < l)         wgt = 1.f-(l-fi)/ctx;
    else if(fi <= rr2) wgt = 0.f;
    else if(fi < tlf)  wgt = 1.f-(fi-rr2)/ctx;
    else               wgt = 0.f;
    float* o = h1 + ((size_t)b*NLQ + i0+ii)*ND;
    o[d]       = wgt*fmaxf(accx[ii], 0.f);
    o[256 + d] = wgt*fmaxf(accy[ii], 0.f);
  }
}

// T[b,j,l] = h1[b,j,:] . v_l   (l = 0..4 -> layers 1..5), stride 8
__global__ __launch_bounds__(256) void k_tv(const float* __restrict__ h1,
                                            const float* __restrict__ v,
                                            float* __restrict__ T){
  int row  = blockIdx.x*4 + (threadIdx.x>>6);
  int lane = threadIdx.x & 63;
  const float4* hr = (const float4*)(h1 + (size_t)row*ND);
  float4 h0 = hr[lane], h1v = hr[lane+64];
  float s0,s1,s2,s3,s4;
  #define DOTV(SL, L) { \
    const float4* vr = (const float4*)(v + (L)*ND); \
    float4 v0 = vr[lane], v1 = vr[lane+64]; \
    float dd = h0.x*v0.x+h0.y*v0.y+h0.z*v0.z+h0.w*v0.w \
             + h1v.x*v1.x+h1v.y*v1.y+h1v.z*v1.z+h1v.w*v1.w; \
    SL = wave_sum(dd); }
  DOTV(s0,0) DOTV(s1,1) DOTV(s2,2) DOTV(s3,3) DOTV(s4,4)
  #undef DOTV
  if(lane==0){
    float* Tp = T + (size_t)row*8;
    Tp[0]=s0; Tp[1]=s1; Tp[2]=s2; Tp[3]=s3; Tp[4]=s4;
  }
}

// R[b*8+k,:] = (k<nk) ? h1[b, l0+k, :] : 0
__global__ __launch_bounds__(256) void k_rows(const float* __restrict__ h1,
                                              const int* __restrict__ left, const int* __restrict__ asp,
                                              float* __restrict__ R){
  int b = blockIdx.x;
  int nk = asp[b], l0 = left[b];
  const float4* src = (const float4*)(h1 + (size_t)b*NLQ*ND);
  float4* dst = (float4*)(R + (size_t)b*8*ND);
  #pragma unroll
  for(int u=0; u<4; u++){
    int f4 = threadIdx.x + u*256;
    int k = f4 >> 7, c = f4 & 127;
    float4 val = (k<nk) ? src[(size_t)(l0+k)*128 + c] : (float4){0.f,0.f,0.f,0.f};
    dst[f4] = val;
  }
}

// fused: att for layers 1..5 aspect rows + y = att @ h1
__global__ __launch_bounds__(256) void k_att5(const float* __restrict__ h1,
    const float* __restrict__ Hasp, const float* __restrict__ T,
    const int* __restrict__ adj, const float* __restrict__ scal,
    const int* __restrict__ left, const int* __restrict__ asp,
    float* __restrict__ y){
  __shared__ float att[5][NLQ];
  int l = blockIdx.x >> 7;
  int b = blockIdx.x & 127;
  int tid = threadIdx.x, lane = tid&63, w = tid>>6;
  int l0 = left[b];
  float S0 = scal[2*(l+1)], S1 = scal[2*(l+1)+1];

  for(int k=w; k<5; k+=4){
    const float2* hrow = (const float2*)(Hasp + (size_t)l*MN + (size_t)(b*8+k)*ND);
    const int* arow = adj + ((size_t)b*NLQ + (l0+k))*NLQ;
    float e[4]; int av[4];
    float m = -3.0e38f;
    #pragma unroll
    for(int q=0;q<4;q++){
      int j = lane + 64*q;
      float2 hp = hrow[j];
      av[q] = arow[j];
      e[q] = fmaxf(S0*hp.x + S1*hp.y + T[((size_t)b*NLQ + j)*8 + l], 0.f);
      if(av[q] > 0) m = fmaxf(m, e[q]);
    }
    m = wave_max(m);
    float pp[4]; float s = 0.f;
    #pragma unroll
    for(int q=0;q<4;q++){
      pp[q] = (av[q] > 0) ? __expf(e[q]-m) : 0.f;
      s += pp[q];
    }
    s = wave_sum(s);
    float inv = 1.f/s;
    #pragma unroll
    for(int q=0;q<4;q++) att[k][lane+64*q] = pp[q]*inv;
  }
  __syncthreads();

  int d = tid;
  const float* hb = h1 + (size_t)b*NLQ*ND;
  float ax[5] = {0,0,0,0,0}, ay[5] = {0,0,0,0,0};
  for(int jj=0; jj<NLQ; jj++){
    float hx = hb[(size_t)jj*ND + d];
    float hy = hb[(size_t)jj*ND + 256 + d];
    #pragma unroll
    for(int k=0;k<5;k++){
      float a = att[k][jj];
      ax[k] += a*hx;
      ay[k] += a*hy;
    }
  }
  float* yb = y + (size_t)l*MN + (size_t)b*8*ND;
  #pragma unroll
  for(int k=0;k<5;k++){
    yb[(size_t)k*ND + d]       = ax[k];
    yb[(size_t)k*ND + 256 + d] = ay[k];
  }
  #pragma unroll
  for(int u=0;u<6;u++) yb[5*ND + u*256 + tid] = 0.f;
}

// g[b,:] = 0.2 * sum_{l,k<nk} relu(hp[l][b*8+k][:])
__global__ __launch_bounds__(256) void k_g(const float* __restrict__ hp,
    const int* __restrict__ asp, float* __restrict__ g){
  int b = blockIdx.x, d = threadIdx.x;
  int nk = asp[b];
  float gx=0.f, gy=0.f;
  for(int l=0;l<5;l++){
    for(int k=0;k<nk;k++){
      const float* r = hp + (size_t)l*MN + (size_t)(b*8+k)*ND;
      gx += fmaxf(r[d], 0.f);
      gy += fmaxf(r[d+256], 0.f);
    }
  }
  g[b*ND + d]       = 0.2f*gx;
  g[b*ND + 256 + d] = 0.2f*gy;
}

// s[b,m] = g[b,:] . x[b,m,:]
__global__ __launch_bounds__(256) void k_dot(const float* __restrict__ x,
    const float* __restrict__ g, float* __restrict__ s){
  int row  = blockIdx.x*4 + (threadIdx.x>>6);
  int b    = row >> 8;
  int lane = threadIdx.x & 63;
  const float4* xr = (const float4*)(x + (size_t)row*ND);
  const float4* gr = (const float4*)(g + (size_t)b*ND);
  float4 x0=xr[lane], x1=xr[lane+64], g0=gr[lane], g1=gr[lane+64];
  float d = x0.x*g0.x + x0.y*g0.y + x0.z*g0.z + x0.w*g0.w
          + x1.x*g1.x + x1.y*g1.y + x1.z*g1.z + x1.w*g1.w;
  d = wave_sum(d);
  if(lane==0) s[row] = d;
}

// alpha = softmax(s[b,:]); out[b,d] = sum_m alpha[m] x[b,m,d]
__global__ __launch_bounds__(256) void k_out(const float* __restrict__ x,
    const float* __restrict__ s, float* __restrict__ out){
  int b  = blockIdx.x >> 2;
  int ch = blockIdx.x & 3;
  int tid = threadIdx.x, lane = tid&63, w = tid>>6;
  __shared__ float red[4];
  __shared__ float alpha[NLQ];
  __shared__ float part[128];
  float sv = s[b*NLQ + tid];
  float m = wave_max(sv);
  if(lane==0) red[w] = m;
  __syncthreads();
  m = fmaxf(fmaxf(red[0],red[1]), fmaxf(red[2],red[3]));
  float p = __expf(sv - m);
  float su = wave_sum(p);
  __syncthreads();
  if(lane==0) red[w] = su;
  __syncthreads();
  su = red[0]+red[1]+red[2]+red[3];
  alpha[tid] = p/su;
  __syncthreads();
  int d = ch*128 + (tid & 127);
  int half = tid >> 7;
  const float* xb = x + (size_t)b*NLQ*ND;
  float acc = 0.f;
  for(int mm = half*128; mm < half*128 + 128; mm++)
    acc += alpha[mm] * xb[(size_t)mm*ND + d];
  if(half) part[tid & 127] = acc;
  __syncthreads();
  if(!half) out[(size_t)b*ND + d] = acc + part[tid & 127];
}

extern "C" void kernel_launch(void* const* d_in, const int* in_sizes, int n_in,
                              void* d_out, int out_size, void* d_ws, size_t ws_size,
                              hipStream_t stream){
  const float* x    = (const float*)d_in[0];
  const float* Wst  = (const float*)d_in[1];
  const float* ast  = (const float*)d_in[2];
  const int*   adj  = (const int*)d_in[3];
  const int*   left = (const int*)d_in[4];
  const int*   asp  = (const int*)d_in[5];
  const int*   tl   = (const int*)d_in[6];
  float* out = (float*)d_out;
  float* ws  = (float*)d_ws;

  const size_t SZ = (size_t)NB*NLQ*ND;
  float* bufA = ws;              // xp, then h1
  float* bufB = ws + SZ;         // h0, then carved small buffers
  float* tbuf = ws + 2*SZ;       // B*L
  float* g    = tbuf + NB*NLQ;   // B*D
  float* scal = g + NB*ND;       // 2*NLAYERS

  // small buffers inside bufB (valid only after k_attn0 has consumed h0)
  float* Hasp = bufB;                         // 5*MN
  float* ybuf = Hasp + (size_t)5*MN;          // 5*MN
  float* hp   = ybuf + (size_t)5*MN;          // 5*MN
  float* T    = hp   + (size_t)5*MN;          // NB*NLQ*8
  float* R    = T + (size_t)NB*NLQ*8;         // 1024*ND
  float* v    = R + (size_t)1024*ND;          // 5*ND
  float* sbuf = v + 5*ND + 64;                // NB*NLQ

  k_scal<<<NLAYERS, 256, 0, stream>>>(ast, scal);
  k_posw<<<NB*NLQ*ND/1024, 256, 0, stream>>>(x, bufA, left, asp, tl);

  // layer 0 (full): h0 = xp @ W0 ; t0 ; full attention -> h1
  k_gemm<<<(NB*NLQ/128)*(ND/128), 256, 0, stream>>>(bufA, Wst, bufB);
  k_t<<<NB*NLQ/4, 256, 0, stream>>>(bufB, ast + ND, tbuf);
  k_attn0<<<NB*8, 256, 0, stream>>>(bufB, adj, tbuf, scal, left, asp, tl, bufA);

  // layers 1..5, restructured: (att @ h1) @ W_l on aspect rows only
  k_wa2<<<5*128, 256, 0, stream>>>(Wst, ast, v);
  k_tv<<<NB*NLQ/4, 256, 0, stream>>>(bufA, v, T);
  k_rows<<<NB, 256, 0, stream>>>(bufA, left, asp, R);
  k_gemm_b<<<5*32, 256, 0, stream>>>(R, 0L, Wst, Hasp);
  k_att5<<<5*NB, 256, 0, stream>>>(bufA, Hasp, T, adj, scal, left, asp, ybuf);
  k_gemm_b<<<5*32, 256, 0, stream>>>(ybuf, (long)MN, Wst, hp);
  k_g<<<NB, 256, 0, stream>>>(hp, asp, g);

  // final attention over original x
  k_dot<<<NB*NLQ/4, 256, 0, stream>>>(x, g, sbuf);
  k_out<<<NB*4, 256, 0, stream>>>(x, sbuf, out);
}